// Round 2
// baseline (1395.171 us; speedup 1.0000x reference)
//
#include <hip/hip_runtime.h>
#include <stdint.h>

#define HD 4096
#define TD 8192

typedef unsigned short u16;
typedef unsigned int u32;
typedef __bf16 bf16x8 __attribute__((ext_vector_type(8)));
typedef float f32x4 __attribute__((ext_vector_type(4)));
typedef float f32x16 __attribute__((ext_vector_type(16)));

// async global->LDS, 16B per lane; LDS dest is wave-uniform base + lane*16,
// so lane l's global chunk must map to ldsbase + l*16 (layouts below do).
#define GL16(gp, lp) __builtin_amdgcn_global_load_lds( \
    (__attribute__((address_space(1))) void*)(void*)(uintptr_t)(gp), \
    (__attribute__((address_space(3))) void*)(lp), 16, 0, 0)

// ---------- NVFP4 quantization helpers ----------

// Round f (>=0) to nearest e4m3fn value (RTNE), returned as the decoded float.
__device__ __forceinline__ float e4m3_rtne(float f) {
  if (f <= 0.0f) return 0.0f;
  unsigned u = __float_as_uint(f);
  int e = (int)((u >> 23) & 0xff) - 127;
  if (e < -6) e = -6;
  float C = __uint_as_float((unsigned)(e + 147) << 23);  // 2^(e+20)
  float r = (f + C) - C;
  return fminf(r, 448.0f);
}

// Quantize 16 fp32 values (one NVFP4 block) with global scale g; write 16
// dequantized (q*s8 = dequant*g) values as bf16 bits (exact: <=6 sig bits).
__device__ __forceinline__ void quant_store16(const float v[16], float g, u16* dst) {
  float amax = 0.0f;
#pragma unroll
  for (int j = 0; j < 16; ++j) amax = fmaxf(amax, fabsf(v[j]));
  float s = e4m3_rtne(amax * g / 6.0f);
  u32 out[8];
  if (s > 0.0f) {
    const float m1 = 0.25f * s, m2 = 0.75f * s, m3 = 1.25f * s, m4 = 1.75f * s;
    const float m5 = 2.5f * s, m6 = 3.5f * s, m7 = 5.0f * s;
#pragma unroll
    for (int p = 0; p < 8; ++p) {
      u16 b[2];
#pragma unroll
      for (int h = 0; h < 2; ++h) {
        float t = v[2 * p + h] * g;
        float u = fabsf(t);
        float q = (u < m4) ? ((u < m2) ? ((u < m1) ? 0.0f : 0.5f)
                                       : ((u < m3) ? 1.0f : 1.5f))
                           : ((u < m6) ? ((u < m5) ? 2.0f : 3.0f)
                                       : ((u < m7) ? 4.0f : 6.0f));
        float val = copysignf(q * s, t);
        b[h] = (u16)(__float_as_uint(val) >> 16);  // exact bf16 truncation
      }
      out[p] = (u32)b[0] | ((u32)b[1] << 16);
    }
  } else {
#pragma unroll
    for (int p = 0; p < 8; ++p) out[p] = 0u;
  }
  uint4* d4 = (uint4*)dst;
  d4[0] = make_uint4(out[0], out[1], out[2], out[3]);
  d4[1] = make_uint4(out[4], out[5], out[6], out[7]);
}

__device__ __forceinline__ float block_sum256(float v) {
#pragma unroll
  for (int off = 32; off > 0; off >>= 1) v += __shfl_down(v, off, 64);
  __shared__ float red[4];
  int tid = threadIdx.x;
  if ((tid & 63) == 0) red[tid >> 6] = v;
  __syncthreads();
  return (red[0] + red[1]) + (red[2] + red[3]);
}

// ---------- elementwise / norm kernels (one block per row, 16 elem/thread) ----------

__global__ __launch_bounds__(256) void k_relu_norm_quant(
    const float* __restrict__ hs, const float* __restrict__ nw,
    const float* __restrict__ agp, float* __restrict__ resid,
    u16* __restrict__ yq) {
  const int row = blockIdx.x, tid = threadIdx.x;
  const size_t base = (size_t)row * HD + tid * 16;
  float v[16];
#pragma unroll
  for (int j = 0; j < 4; ++j) ((float4*)v)[j] = ((const float4*)(hs + base))[j];
  float ss = 0.0f;
#pragma unroll
  for (int j = 0; j < 16; ++j) {
    v[j] = fmaxf(v[j], 0.0f);
    ss += v[j] * v[j];
  }
#pragma unroll
  for (int j = 0; j < 4; ++j) ((float4*)(resid + base))[j] = ((float4*)v)[j];
  float tot = block_sum256(ss);
  float rs = 1.0f / sqrtf(tot * (1.0f / HD) + 1e-6f);
  const float* nwp = nw + tid * 16;  // norm_w[0]
  float y[16];
#pragma unroll
  for (int j = 0; j < 16; ++j) y[j] = v[j] * rs * nwp[j];
  quant_store16(y, agp[0], yq + base);
}

__global__ __launch_bounds__(256) void k_norm_quant(
    const float* __restrict__ resid, const float* __restrict__ nw,
    const float* __restrict__ agp, int li, u16* __restrict__ yq) {
  const int row = blockIdx.x, tid = threadIdx.x;
  const size_t base = (size_t)row * HD + tid * 16;
  float v[16];
#pragma unroll
  for (int j = 0; j < 4; ++j) ((float4*)v)[j] = ((const float4*)(resid + base))[j];
  float ss = 0.0f;
#pragma unroll
  for (int j = 0; j < 16; ++j) ss += v[j] * v[j];
  float tot = block_sum256(ss);
  float rs = 1.0f / sqrtf(tot * (1.0f / HD) + 1e-6f);
  const float* nwp = nw + (size_t)li * HD + tid * 16;
  float y[16];
#pragma unroll
  for (int j = 0; j < 16; ++j) y[j] = v[j] * rs * nwp[j];
  quant_store16(y, agp[li], yq + base);
}

__global__ __launch_bounds__(256) void k_final_norm(
    float* __restrict__ io, const float* __restrict__ nw) {
  const int row = blockIdx.x, tid = threadIdx.x;
  const size_t base = (size_t)row * HD + tid * 16;
  float v[16];
#pragma unroll
  for (int j = 0; j < 4; ++j) ((float4*)v)[j] = ((const float4*)(io + base))[j];
  float ss = 0.0f;
#pragma unroll
  for (int j = 0; j < 16; ++j) ss += v[j] * v[j];
  float tot = block_sum256(ss);
  float rs = 1.0f / sqrtf(tot * (1.0f / HD) + 1e-6f);
  const float* nwp = nw + (size_t)3 * HD + tid * 16;
#pragma unroll
  for (int j = 0; j < 16; ++j) v[j] = v[j] * rs * nwp[j];
#pragma unroll
  for (int j = 0; j < 4; ++j) ((float4*)(io + base))[j] = ((float4*)v)[j];
}

__global__ __launch_bounds__(256) void k_quant_w(
    const float* __restrict__ w, const float* __restrict__ wgp, int li,
    u16* __restrict__ wq) {
  const int row = blockIdx.x, tid = threadIdx.x;
  const size_t base = (size_t)li * HD * HD + (size_t)row * HD + tid * 16;
  float v[16];
#pragma unroll
  for (int j = 0; j < 4; ++j) ((float4*)v)[j] = ((const float4*)(w + base))[j];
  quant_store16(v, wgp[li], wq + (size_t)row * HD + tid * 16);
}

// all 3 layers in one dispatch (rows 0..3*HD); wq3 laid out [l][HD][HD]
__global__ __launch_bounds__(256) void k_quant_w_all(
    const float* __restrict__ w, const float* __restrict__ wgp,
    u16* __restrict__ wq3) {
  const int row = blockIdx.x, tid = threadIdx.x;
  const size_t base = (size_t)row * HD + tid * 16;
  float v[16];
#pragma unroll
  for (int j = 0; j < 4; ++j) ((float4*)v)[j] = ((const float4*)(w + base))[j];
  quant_store16(v, wgp[row >> 12], wq3 + base);
}

// ---------- bf16 GEMM, 256x256 8-phase schedule: z = A @ B^T, resid += z*alpha ----------
// A [TD, HD] bf16 bits, B [HD, HD] bf16 bits (B row = output col).
// BM=BN=256, BK=64. 8 waves = 2(M) x 4(N); per-wave output 128x64 = 4x2
// tiles of mfma_f32_32x32x16_bf16 (4 k-steps of 16 per K-tile).
// LDS: 2 buffers x [256 rows][64] bf16 per operand = 128 KiB (buf0 even
// K-tiles, buf1 odd).
//
// Swizzle (both-sides, rule #21): 16B chunk kc of row m lives at LDS chunk
// kc ^ (m&7); staging keeps LDS linear and pre-swizzles the GLOBAL source
// column; ds_read_b128 applies the same XOR (wave-uniform per lane since
// all fragment rows are +32-aligned: row&7 == lane&7).
//
// Fragment layouts (32x32x16 family, mirrors the proven 16x16x32 rule):
//   A/B: lane l holds row/col = l&31, k = (l>>5)*8 .. +7 (one b128)
//   C/D: col = l&31, row = (reg&3) + 8*(reg>>2) + 4*(l>>5)   [m74/m101]
//
// Phase schedule per iteration (2 K-tiles: 2i in buf0, 2i+1 in buf1);
// reads {16,0,8,0} per K-tile, stage slots and vmcnt(6) points exactly as
// verified in round 1 (see ph comments).
//
// Epilogue: drain vmcnt(0) (late wrapped-prefetch GL16s still target LDS!),
// then per 128-row half: repack acc into LDS as fp32 [128][256] (rows 0-63
// in ldsA, 64-127 in ldsB), barrier, coalesced float4 rmw of resid.

#define BARF() do { asm volatile("" ::: "memory"); \
    __builtin_amdgcn_s_barrier(); \
    asm volatile("" ::: "memory"); } while (0)
#define WLG() asm volatile("s_waitcnt lgkmcnt(0)" ::: "memory")
#define WVM6() asm volatile("s_waitcnt vmcnt(6)" ::: "memory")

__global__ __launch_bounds__(512, 2) void k_gemm(
    const u16* __restrict__ A, const u16* __restrict__ B,
    float* __restrict__ resid, const float* __restrict__ agp,
    const float* __restrict__ wgp, int layer) {
  __shared__ __align__(16) u16 ldsA[2 * 256 * 64];  // [buf][row][64]
  __shared__ __align__(16) u16 ldsB[2 * 256 * 64];
  const int tid = threadIdx.x;
  const int lane = tid & 63, wave = tid >> 6;
  const int wr = wave >> 2, wc = wave & 3;     // 2 x 4 wave grid
  const int l31 = lane & 31, l5 = lane >> 5, l7 = lane & 7;

  int bid = blockIdx.x;
  bid = (bid & 7) * 64 + (bid >> 3);  // XCD-contiguous chunks (512 % 8 == 0)
  const int m0 = (bid >> 4) * 256;
  const int n0 = (bid & 15) * 256;

  // ---- staging constants: chunk c=tid (+512) -> lds half-tile byte c*16;
  // global row = half*128 + (c>>3), colchunk = (c&7) ^ ((c>>3)&7).
  const int rs = tid >> 3;
  const int cs = ((tid & 7) ^ (rs & 7)) * 8;
  const u16* gA = A + (size_t)(m0 + rs) * HD + cs;
  const u16* gB = B + (size_t)(n0 + rs) * HD + cs;
  u16* lA = ldsA + tid * 8;
  u16* lB = ldsB + tid * 8;

#define STG_A(bb, h, koff) do { \
    GL16(gA + (size_t)(h) * (128 * HD) + (koff), lA + (bb) + (h) * 8192); \
    GL16(gA + (size_t)(h) * (128 * HD) + 64 * HD + (koff), lA + (bb) + (h) * 8192 + 4096); \
  } while (0)
#define STG_B(bb, h, koff) do { \
    GL16(gB + (size_t)(h) * (128 * HD) + (koff), lB + (bb) + (h) * 8192); \
    GL16(gB + (size_t)(h) * (128 * HD) + 64 * HD + (koff), lB + (bb) + (h) * 8192 + 4096); \
  } while (0)

  // ---- fragment-read constants (u16-element offsets into a 256x64 buffer)
  const int wm = wr * 128, wn = wc * 64;
  const int aoff = (wm + l31) * 64;
  const int boff = (wn + l31) * 64;
  const int ck[4] = {((0 + l5) ^ l7) * 8, ((2 + l5) ^ l7) * 8,
                     ((4 + l5) ^ l7) * 8, ((6 + l5) ^ l7) * 8};

  f32x16 acc[4][2];
#pragma unroll
  for (int i = 0; i < 4; ++i)
#pragma unroll
    for (int j = 0; j < 2; ++j)
#pragma unroll
      for (int p = 0; p < 16; ++p) acc[i][j][p] = 0.0f;

  bf16x8 a[2][4], b[2][4];

#define LD_A32(base, mh) do { \
    _Pragma("unroll") \
    for (int mi = 0; mi < 2; ++mi) \
    _Pragma("unroll") \
    for (int ks = 0; ks < 4; ++ks) \
      a[mi][ks] = *(const bf16x8*)((base) + aoff + ((mh) * 2 + mi) * 2048 + ck[ks]); \
  } while (0)
#define LD_B32(base) do { \
    _Pragma("unroll") \
    for (int nj = 0; nj < 2; ++nj) \
    _Pragma("unroll") \
    for (int ks = 0; ks < 4; ++ks) \
      b[nj][ks] = *(const bf16x8*)((base) + boff + nj * 2048 + ck[ks]); \
  } while (0)
#define MMQ32(mh, nh) do { \
    _Pragma("unroll") \
    for (int ks = 0; ks < 4; ++ks) { \
      acc[(mh) * 2 + 0][nh] = __builtin_amdgcn_mfma_f32_32x32x16_bf16( \
          a[0][ks], b[nh][ks], acc[(mh) * 2 + 0][nh], 0, 0, 0); \
      acc[(mh) * 2 + 1][nh] = __builtin_amdgcn_mfma_f32_32x32x16_bf16( \
          a[1][ks], b[nh][ks], acc[(mh) * 2 + 1][nh], 0, 0, 0); \
    } } while (0)

  // ---- prologue: tile0 -> buf0 (all 4 half-tiles), tile1 -> buf1 (B0,B1,A0).
  // vmcnt(6) forces exactly the 8 buf0 loads landed; buf1's 6 stay in flight.
  STG_B(0, 0, 0); STG_B(0, 1, 0);
  STG_A(0, 0, 0); STG_A(0, 1, 0);
  STG_B(16384, 0, 64); STG_B(16384, 1, 64);
  STG_A(16384, 0, 64);
  WVM6();
  BARF();

  for (int i = 0; i < 32; ++i) {
    const int kb = i * 128;
    const int k1 = kb + 64;                       // tile 2i+1 (never wraps)
    int k2 = kb + 128; if (k2 >= HD) k2 -= HD;    // tile 2i+2 (wrap last iter)
    int k3 = kb + 192; if (k3 >= HD) k3 -= HD;    // tile 2i+3
    // ph1: buf0 Q(mh0,nh0); stage buf1.A1[2i+1]
    LD_A32(ldsA, 0); LD_B32(ldsB);
    STG_A(16384, 1, k1);
    BARF(); WLG();
    __builtin_amdgcn_s_setprio(1); MMQ32(0, 0); __builtin_amdgcn_s_setprio(0);
    BARF();
    // ph2: Q(mh0,nh1); stage buf0.B0[2i+2]
    STG_B(0, 0, k2);
    BARF();
    __builtin_amdgcn_s_setprio(1); MMQ32(0, 1); __builtin_amdgcn_s_setprio(0);
    BARF();
    // ph3: Q(mh1,nh0); stage buf0.B1
    LD_A32(ldsA, 1);
    STG_B(0, 1, k2);
    BARF(); WLG();
    __builtin_amdgcn_s_setprio(1); MMQ32(1, 0); __builtin_amdgcn_s_setprio(0);
    BARF();
    // ph4: Q(mh1,nh1); stage buf0.A0; counted vmcnt -> buf1 fully landed
    STG_A(0, 0, k2);
    WVM6();
    BARF();
    __builtin_amdgcn_s_setprio(1); MMQ32(1, 1); __builtin_amdgcn_s_setprio(0);
    BARF();
    // ph5: buf1 Q(mh0,nh0); stage buf0.A1
    LD_A32(ldsA + 16384, 0); LD_B32(ldsB + 16384);
    STG_A(0, 1, k2);
    BARF(); WLG();
    __builtin_amdgcn_s_setprio(1); MMQ32(0, 0); __builtin_amdgcn_s_setprio(0);
    BARF();
    // ph6: Q(mh0,nh1); stage buf1.B0[2i+3]
    STG_B(16384, 0, k3);
    BARF();
    __builtin_amdgcn_s_setprio(1); MMQ32(0, 1); __builtin_amdgcn_s_setprio(0);
    BARF();
    // ph7: Q(mh1,nh0); stage buf1.B1
    LD_A32(ldsA + 16384, 1);
    STG_B(16384, 1, k3);
    BARF(); WLG();
    __builtin_amdgcn_s_setprio(1); MMQ32(1, 0); __builtin_amdgcn_s_setprio(0);
    BARF();
    // ph8: Q(mh1,nh1); stage buf1.A0; counted vmcnt -> buf0 fully landed
    STG_A(16384, 0, k3);
    WVM6();
    BARF();
    __builtin_amdgcn_s_setprio(1); MMQ32(1, 1); __builtin_amdgcn_s_setprio(0);
    BARF();
  }

  // ---- epilogue: drain ALL outstanding GL16 LDS-writes before reusing LDS
  asm volatile("s_waitcnt vmcnt(0)" ::: "memory");
  __syncthreads();

  const float alpha = 1.0f / (agp[layer] * wgp[layer]);
  float* const fA = (float*)ldsA;  // 64 rows x 256 cols fp32
  float* const fB = (float*)ldsB;
#pragma unroll
  for (int h = 0; h < 2; ++h) {
    if (wr == h) {
      // C/D: col = l31, row-in-tile = (p&3) + 8*(p>>2) + 4*l5
#pragma unroll
      for (int mt = 0; mt < 4; ++mt) {
        float* const f = (mt < 2) ? fA : fB;
        const int rb = (mt & 1) * 32;
#pragma unroll
        for (int nj = 0; nj < 2; ++nj) {
          const int col = wn + nj * 32 + l31;
#pragma unroll
          for (int p = 0; p < 16; ++p) {
            const int rowp = rb + (p & 3) + 8 * (p >> 2) + 4 * l5;
            f[rowp * 256 + col] = acc[mt][nj][p];
          }
        }
      }
    }
    __syncthreads();
    // coalesced float4 read-modify-write of resid
#pragma unroll
    for (int p = 0; p < 16; ++p) {
      const float* const f = (p < 8) ? fA : fB;
      const int idx = (p & 7) * 512 + tid;   // 0..4095 within half-of-half
      const int lrow = (p < 8 ? 0 : 64) + (idx >> 6);
      const int c4 = idx & 63;
      f32x4 v = *(const f32x4*)&f[(idx >> 6) * 256 + c4 * 4];
      float4* gp = (float4*)(resid + (size_t)(m0 + h * 128 + lrow) * HD + n0) + c4;
      float4 o = *gp;
      o.x = fmaf(v[0], alpha, o.x);
      o.y = fmaf(v[1], alpha, o.y);
      o.z = fmaf(v[2], alpha, o.z);
      o.w = fmaf(v[3], alpha, o.w);
      *gp = o;
    }
    if (h == 0) __syncthreads();  // protect fA/fB before half-1 repack
  }
}

// ---------- host ----------

extern "C" void kernel_launch(void* const* d_in, const int* in_sizes, int n_in,
                              void* d_out, int out_size, void* d_ws, size_t ws_size,
                              hipStream_t stream) {
  const float* hs = (const float*)d_in[0];
  const float* nw = (const float*)d_in[1];
  const float* w = (const float*)d_in[2];
  const float* ag = (const float*)d_in[3];
  const float* wg = (const float*)d_in[4];
  float* out = (float*)d_out;  // fp32 resid scratch; final y overwrites in place

  const size_t need_big = ((size_t)3 * HD * HD + (size_t)TD * HD) * sizeof(u16);
  if (ws_size >= need_big) {
    u16* wq3 = (u16*)d_ws;                        // 3*HD*HD bf16 bits (96 MiB)
    u16* yq = wq3 + (size_t)3 * HD * HD;          // TD*HD bf16 bits (64 MiB)
    k_quant_w_all<<<3 * HD, 256, 0, stream>>>(w, wg, wq3);
    k_relu_norm_quant<<<TD, 256, 0, stream>>>(hs, nw, ag, out, yq);
    for (int l = 0; l < 3; ++l) {
      k_gemm<<<dim3((TD / 256) * (HD / 256)), 512, 0, stream>>>(
          yq, wq3 + (size_t)l * HD * HD, out, ag, wg, l);
      if (l < 2) k_norm_quant<<<TD, 256, 0, stream>>>(out, nw, ag, l + 1, yq);
    }
  } else {
    u16* wq = (u16*)d_ws;                    // HD*HD bf16 bits, reused per layer
    u16* yq = (u16*)d_ws + (size_t)HD * HD;  // TD*HD bf16 bits
    k_relu_norm_quant<<<TD, 256, 0, stream>>>(hs, nw, ag, out, yq);
    for (int l = 0; l < 3; ++l) {
      k_quant_w<<<HD, 256, 0, stream>>>(w, wg, l, wq);
      k_gemm<<<dim3((TD / 256) * (HD / 256)), 512, 0, stream>>>(yq, wq, out, ag, wg, l);
      if (l < 2) k_norm_quant<<<TD, 256, 0, stream>>>(out, nw, ag, l + 1, yq);
    }
  }
  k_final_norm<<<TD, 256, 0, stream>>>(out, nw);
}

// Round 3
// 1355.988 us; speedup vs baseline: 1.0289x; 1.0289x over previous
//
#include <hip/hip_runtime.h>
#include <stdint.h>

#define HD 4096
#define TD 8192

typedef unsigned short u16;
typedef unsigned int u32;
typedef __bf16 bf16x8 __attribute__((ext_vector_type(8)));
typedef float f32x4 __attribute__((ext_vector_type(4)));

// async global->LDS, 16B per lane; LDS dest is wave-uniform base + lane*16,
// so lane l's global chunk must map to ldsbase + l*16 (layouts below do).
#define GL16(gp, lp) __builtin_amdgcn_global_load_lds( \
    (__attribute__((address_space(1))) void*)(void*)(uintptr_t)(gp), \
    (__attribute__((address_space(3))) void*)(lp), 16, 0, 0)

// ---------- NVFP4 quantization helpers ----------

// Round f (>=0) to nearest e4m3fn value (RTNE), returned as the decoded float.
__device__ __forceinline__ float e4m3_rtne(float f) {
  if (f <= 0.0f) return 0.0f;
  unsigned u = __float_as_uint(f);
  int e = (int)((u >> 23) & 0xff) - 127;
  if (e < -6) e = -6;
  float C = __uint_as_float((unsigned)(e + 147) << 23);  // 2^(e+20)
  float r = (f + C) - C;
  return fminf(r, 448.0f);
}

// Quantize 16 fp32 values (one NVFP4 block) with global scale g; write 16
// dequantized (q*s8 = dequant*g) values as bf16 bits (exact: <=6 sig bits).
__device__ __forceinline__ void quant_store16(const float v[16], float g, u16* dst) {
  float amax = 0.0f;
#pragma unroll
  for (int j = 0; j < 16; ++j) amax = fmaxf(amax, fabsf(v[j]));
  float s = e4m3_rtne(amax * g / 6.0f);
  u32 out[8];
  if (s > 0.0f) {
    const float m1 = 0.25f * s, m2 = 0.75f * s, m3 = 1.25f * s, m4 = 1.75f * s;
    const float m5 = 2.5f * s, m6 = 3.5f * s, m7 = 5.0f * s;
#pragma unroll
    for (int p = 0; p < 8; ++p) {
      u16 b[2];
#pragma unroll
      for (int h = 0; h < 2; ++h) {
        float t = v[2 * p + h] * g;
        float u = fabsf(t);
        float q = (u < m4) ? ((u < m2) ? ((u < m1) ? 0.0f : 0.5f)
                                       : ((u < m3) ? 1.0f : 1.5f))
                           : ((u < m6) ? ((u < m5) ? 2.0f : 3.0f)
                                       : ((u < m7) ? 4.0f : 6.0f));
        float val = copysignf(q * s, t);
        b[h] = (u16)(__float_as_uint(val) >> 16);  // exact bf16 truncation
      }
      out[p] = (u32)b[0] | ((u32)b[1] << 16);
    }
  } else {
#pragma unroll
    for (int p = 0; p < 8; ++p) out[p] = 0u;
  }
  uint4* d4 = (uint4*)dst;
  d4[0] = make_uint4(out[0], out[1], out[2], out[3]);
  d4[1] = make_uint4(out[4], out[5], out[6], out[7]);
}

// ---------- elementwise / norm kernels (wave-per-row, 4 rows per block) ----------
// Lane owns 4 NVFP4 blocks: cols c*1024 + lane*16 .. +15 (c = 0..3).
// Row reduction is a pure 6-step shfl_xor across the wave: no LDS, no
// __syncthreads -> stores are not serialized behind block-wide barriers.

__global__ __launch_bounds__(256) void k_relu_norm_quant(
    const float* __restrict__ hs, const float* __restrict__ nw,
    const float* __restrict__ agp, float* __restrict__ resid,
    u16* __restrict__ yq) {
  const int lane = threadIdx.x & 63;
  const int row = blockIdx.x * 4 + (threadIdx.x >> 6);
  const size_t base = (size_t)row * HD;
  float v[64];
#pragma unroll
  for (int c = 0; c < 4; ++c)
#pragma unroll
    for (int j = 0; j < 4; ++j)
      ((float4*)v)[c * 4 + j] =
          ((const float4*)(hs + base + c * 1024 + lane * 16))[j];
  float ss = 0.0f;
#pragma unroll
  for (int j = 0; j < 64; ++j) {
    v[j] = fmaxf(v[j], 0.0f);
    ss += v[j] * v[j];
  }
#pragma unroll
  for (int c = 0; c < 4; ++c)
#pragma unroll
    for (int j = 0; j < 4; ++j)
      ((float4*)(resid + base + c * 1024 + lane * 16))[j] = ((float4*)v)[c * 4 + j];
#pragma unroll
  for (int off = 32; off > 0; off >>= 1) ss += __shfl_xor(ss, off, 64);
  const float rs = 1.0f / sqrtf(ss * (1.0f / HD) + 1e-6f);
  const float g = agp[0];
  const float* nwp = nw;  // norm_w[0]
#pragma unroll
  for (int c = 0; c < 4; ++c) {
    float y[16];
#pragma unroll
    for (int j = 0; j < 16; ++j)
      y[j] = v[c * 16 + j] * rs * nwp[c * 1024 + lane * 16 + j];
    quant_store16(y, g, yq + base + c * 1024 + lane * 16);
  }
}

__global__ __launch_bounds__(256) void k_norm_quant(
    const float* __restrict__ resid, const float* __restrict__ nw,
    const float* __restrict__ agp, int li, u16* __restrict__ yq) {
  const int lane = threadIdx.x & 63;
  const int row = blockIdx.x * 4 + (threadIdx.x >> 6);
  const size_t base = (size_t)row * HD;
  float v[64];
#pragma unroll
  for (int c = 0; c < 4; ++c)
#pragma unroll
    for (int j = 0; j < 4; ++j)
      ((float4*)v)[c * 4 + j] =
          ((const float4*)(resid + base + c * 1024 + lane * 16))[j];
  float ss = 0.0f;
#pragma unroll
  for (int j = 0; j < 64; ++j) ss += v[j] * v[j];
#pragma unroll
  for (int off = 32; off > 0; off >>= 1) ss += __shfl_xor(ss, off, 64);
  const float rs = 1.0f / sqrtf(ss * (1.0f / HD) + 1e-6f);
  const float g = agp[li];
  const float* nwp = nw + (size_t)li * HD;
#pragma unroll
  for (int c = 0; c < 4; ++c) {
    float y[16];
#pragma unroll
    for (int j = 0; j < 16; ++j)
      y[j] = v[c * 16 + j] * rs * nwp[c * 1024 + lane * 16 + j];
    quant_store16(y, g, yq + base + c * 1024 + lane * 16);
  }
}

__global__ __launch_bounds__(256) void k_final_norm(
    float* __restrict__ io, const float* __restrict__ nw) {
  const int lane = threadIdx.x & 63;
  const int row = blockIdx.x * 4 + (threadIdx.x >> 6);
  const size_t base = (size_t)row * HD;
  float v[64];
#pragma unroll
  for (int c = 0; c < 4; ++c)
#pragma unroll
    for (int j = 0; j < 4; ++j)
      ((float4*)v)[c * 4 + j] =
          ((const float4*)(io + base + c * 1024 + lane * 16))[j];
  float ss = 0.0f;
#pragma unroll
  for (int j = 0; j < 64; ++j) ss += v[j] * v[j];
#pragma unroll
  for (int off = 32; off > 0; off >>= 1) ss += __shfl_xor(ss, off, 64);
  const float rs = 1.0f / sqrtf(ss * (1.0f / HD) + 1e-6f);
  const float* nwp = nw + (size_t)3 * HD;
#pragma unroll
  for (int c = 0; c < 4; ++c) {
#pragma unroll
    for (int j = 0; j < 16; ++j)
      v[c * 16 + j] = v[c * 16 + j] * rs * nwp[c * 1024 + lane * 16 + j];
#pragma unroll
    for (int j = 0; j < 4; ++j)
      ((float4*)(io + base + c * 1024 + lane * 16))[j] = ((float4*)v)[c * 4 + j];
  }
}

__global__ __launch_bounds__(256) void k_quant_w(
    const float* __restrict__ w, const float* __restrict__ wgp, int li,
    u16* __restrict__ wq) {
  const int row = blockIdx.x, tid = threadIdx.x;
  const size_t base = (size_t)li * HD * HD + (size_t)row * HD + tid * 16;
  float v[16];
#pragma unroll
  for (int j = 0; j < 4; ++j) ((float4*)v)[j] = ((const float4*)(w + base))[j];
  quant_store16(v, wgp[li], wq + (size_t)row * HD + tid * 16);
}

// all 3 layers in one dispatch (rows 0..3*HD); wq3 laid out [l][HD][HD]
__global__ __launch_bounds__(256) void k_quant_w_all(
    const float* __restrict__ w, const float* __restrict__ wgp,
    u16* __restrict__ wq3) {
  const int row = blockIdx.x, tid = threadIdx.x;
  const size_t base = (size_t)row * HD + tid * 16;
  float v[16];
#pragma unroll
  for (int j = 0; j < 4; ++j) ((float4*)v)[j] = ((const float4*)(w + base))[j];
  quant_store16(v, wgp[row >> 12], wq3 + base);
}

// ---------- bf16 GEMM, 256x256 8-phase schedule: z = A @ B^T, resid += z*alpha ----------
// EXACT round-1 known-good structure (291 us, zero LDS bank conflicts).
// A [TD, HD] bf16 bits, B [HD, HD] bf16 bits (B row = output col).
// BM=BN=256, BK=64. 8 waves = 2(M) x 4(N); per-wave output 128x64 = 8x4
// mfma_f32_16x16x32_bf16 frags. LDS: 2 buffers x [256 rows][64] bf16 per
// operand = 128 KiB. buf0 holds even K-tiles, buf1 odd (fixed roles).
//
// Swizzle (both-sides, rule #21): 16B chunk kc of row m lives at LDS chunk
// kc ^ (m&7); staging keeps LDS linear and pre-swizzles the GLOBAL source
// column; ds_read_b128 applies the same XOR.
//
// Phase schedule per iteration (2 K-tiles: 2i in buf0, 2i+1 in buf1).
// Reads: ph1: buf0 A-mh0(8) + B-all(8); ph3: buf0 A-mh1(8); ph5/ph7 same on
// buf1. Stage slots (1 half-tile = 2 global_load_lds per thread, per phase):
//   ph1: buf1.A1[t=2i+1]  ph2: buf0.B0[t=2i+2]  ph3: buf0.B1  ph4: buf0.A0
//   ph5: buf0.A1          ph6: buf1.B0[t=2i+3]  ph7: buf1.B1  ph8: buf1.A0
// Counted vmcnt(6) (=3 half-tiles in flight) at ph4 and ph8 only.

#define BARF() do { asm volatile("" ::: "memory"); \
    __builtin_amdgcn_s_barrier(); \
    asm volatile("" ::: "memory"); } while (0)
#define WLG() asm volatile("s_waitcnt lgkmcnt(0)" ::: "memory")
#define WVM6() asm volatile("s_waitcnt vmcnt(6)" ::: "memory")

__global__ __launch_bounds__(512, 2) void k_gemm(
    const u16* __restrict__ A, const u16* __restrict__ B,
    float* __restrict__ resid, const float* __restrict__ agp,
    const float* __restrict__ wgp, int layer) {
  __shared__ __align__(16) u16 ldsA[2 * 256 * 64];  // [buf][row][64]
  __shared__ __align__(16) u16 ldsB[2 * 256 * 64];
  const int tid = threadIdx.x;
  const int lane = tid & 63, wave = tid >> 6;
  const int wr = wave >> 2, wc = wave & 3;     // 2 x 4 wave grid
  const int r = lane & 15, q = lane >> 4;

  int bid = blockIdx.x;
  bid = (bid & 7) * 64 + (bid >> 3);  // XCD-contiguous chunks (512 % 8 == 0)
  const int m0 = (bid >> 4) * 256;
  const int n0 = (bid & 15) * 256;

  // ---- staging constants: chunk c=tid (+512) -> lds half-tile byte c*16;
  // global row = half*128 + (c>>3), colchunk = (c&7) ^ ((c>>3)&7).
  const int rs = tid >> 3;
  const int cs = ((tid & 7) ^ (rs & 7)) * 8;
  const u16* gA = A + (size_t)(m0 + rs) * HD + cs;
  const u16* gB = B + (size_t)(n0 + rs) * HD + cs;
  u16* lA = ldsA + tid * 8;
  u16* lB = ldsB + tid * 8;

#define STG_A(bb, h, koff) do { \
    GL16(gA + (size_t)(h) * (128 * HD) + (koff), lA + (bb) + (h) * 8192); \
    GL16(gA + (size_t)(h) * (128 * HD) + 64 * HD + (koff), lA + (bb) + (h) * 8192 + 4096); \
  } while (0)
#define STG_B(bb, h, koff) do { \
    GL16(gB + (size_t)(h) * (128 * HD) + (koff), lB + (bb) + (h) * 8192); \
    GL16(gB + (size_t)(h) * (128 * HD) + 64 * HD + (koff), lB + (bb) + (h) * 8192 + 4096); \
  } while (0)

  // ---- fragment-read constants (element offsets into a 256x64 buffer)
  const int sa = (q ^ (r & 7)) * 8;        // kk=0 swizzled chunk
  const int sb = ((q + 4) ^ (r & 7)) * 8;  // kk=1
  const int arow = (wr * 128 + r) * 64;
  const int brow = (wc * 64 + r) * 64;

  f32x4 acc[8][4];
#pragma unroll
  for (int i = 0; i < 8; ++i)
#pragma unroll
    for (int j = 0; j < 4; ++j) acc[i][j] = (f32x4){0.f, 0.f, 0.f, 0.f};

  bf16x8 a[4][2], b[4][2];

#define LD_A(base) do { \
    _Pragma("unroll") \
    for (int mi = 0; mi < 4; ++mi) { \
      a[mi][0] = *(const bf16x8*)((base) + arow + mi * 1024 + sa); \
      a[mi][1] = *(const bf16x8*)((base) + arow + mi * 1024 + sb); \
    } } while (0)
#define LD_B(base) do { \
    _Pragma("unroll") \
    for (int nj = 0; nj < 4; ++nj) { \
      b[nj][0] = *(const bf16x8*)((base) + brow + nj * 1024 + sa); \
      b[nj][1] = *(const bf16x8*)((base) + brow + nj * 1024 + sb); \
    } } while (0)
#define MMQ(mh, nh) do { \
    _Pragma("unroll") \
    for (int mi = 0; mi < 4; ++mi) \
    _Pragma("unroll") \
    for (int nj = 0; nj < 2; ++nj) { \
      acc[(mh) * 4 + mi][(nh) * 2 + nj] = __builtin_amdgcn_mfma_f32_16x16x32_bf16( \
          a[mi][0], b[(nh) * 2 + nj][0], acc[(mh) * 4 + mi][(nh) * 2 + nj], 0, 0, 0); \
      acc[(mh) * 4 + mi][(nh) * 2 + nj] = __builtin_amdgcn_mfma_f32_16x16x32_bf16( \
          a[mi][1], b[(nh) * 2 + nj][1], acc[(mh) * 4 + mi][(nh) * 2 + nj], 0, 0, 0); \
    } } while (0)

  // ---- prologue: tile0 -> buf0 (all 4 half-tiles), tile1 -> buf1 (B0,B1,A0).
  // vmcnt(6) forces exactly the 8 buf0 loads landed; buf1's 6 stay in flight.
  STG_B(0, 0, 0); STG_B(0, 1, 0);
  STG_A(0, 0, 0); STG_A(0, 1, 0);
  STG_B(16384, 0, 64); STG_B(16384, 1, 64);
  STG_A(16384, 0, 64);
  WVM6();
  BARF();

  for (int i = 0; i < 32; ++i) {
    const int kb = i * 128;
    const int k1 = kb + 64;                       // tile 2i+1 (never wraps)
    int k2 = kb + 128; if (k2 >= HD) k2 -= HD;    // tile 2i+2 (wrap last iter)
    int k3 = kb + 192; if (k3 >= HD) k3 -= HD;    // tile 2i+3
    // ph1: buf0 Q(mh0,nh0); stage buf1.A1[2i+1]
    LD_A(ldsA); LD_B(ldsB);
    STG_A(16384, 1, k1);
    BARF(); WLG();
    __builtin_amdgcn_s_setprio(1); MMQ(0, 0); __builtin_amdgcn_s_setprio(0);
    BARF();
    // ph2: Q(mh0,nh1); stage buf0.B0[2i+2]
    STG_B(0, 0, k2);
    BARF();
    __builtin_amdgcn_s_setprio(1); MMQ(0, 1); __builtin_amdgcn_s_setprio(0);
    BARF();
    // ph3: Q(mh1,nh0); stage buf0.B1
    LD_A(ldsA + 4096);
    STG_B(0, 1, k2);
    BARF(); WLG();
    __builtin_amdgcn_s_setprio(1); MMQ(1, 0); __builtin_amdgcn_s_setprio(0);
    BARF();
    // ph4: Q(mh1,nh1); stage buf0.A0; counted vmcnt -> buf1 fully landed
    STG_A(0, 0, k2);
    WVM6();
    BARF();
    __builtin_amdgcn_s_setprio(1); MMQ(1, 1); __builtin_amdgcn_s_setprio(0);
    BARF();
    // ph5: buf1 Q(mh0,nh0); stage buf0.A1
    LD_A(ldsA + 16384); LD_B(ldsB + 16384);
    STG_A(0, 1, k2);
    BARF(); WLG();
    __builtin_amdgcn_s_setprio(1); MMQ(0, 0); __builtin_amdgcn_s_setprio(0);
    BARF();
    // ph6: Q(mh0,nh1); stage buf1.B0[2i+3]
    STG_B(16384, 0, k3);
    BARF();
    __builtin_amdgcn_s_setprio(1); MMQ(0, 1); __builtin_amdgcn_s_setprio(0);
    BARF();
    // ph7: Q(mh1,nh0); stage buf1.B1
    LD_A(ldsA + 16384 + 4096);
    STG_B(16384, 1, k3);
    BARF(); WLG();
    __builtin_amdgcn_s_setprio(1); MMQ(1, 0); __builtin_amdgcn_s_setprio(0);
    BARF();
    // ph8: Q(mh1,nh1); stage buf1.A0; counted vmcnt -> buf0 fully landed
    STG_A(16384, 0, k3);
    WVM6();
    BARF();
    __builtin_amdgcn_s_setprio(1); MMQ(1, 1); __builtin_amdgcn_s_setprio(0);
    BARF();
  }

  const float alpha = 1.0f / (agp[layer] * wgp[layer]);
  // C/D layout: col = lane&15 (n), row = (lane>>4)*4 + reg (m)
#pragma unroll
  for (int mi = 0; mi < 8; ++mi) {
    const int gm0 = m0 + wr * 128 + mi * 16 + q * 4;
#pragma unroll
    for (int nj = 0; nj < 4; ++nj) {
      const int gn = n0 + wc * 64 + nj * 16 + r;
#pragma unroll
      for (int t = 0; t < 4; ++t) {
        float* p = resid + (size_t)(gm0 + t) * HD + gn;
        *p = fmaf(acc[mi][nj][t], alpha, *p);
      }
    }
  }
}

// ---------- host ----------

extern "C" void kernel_launch(void* const* d_in, const int* in_sizes, int n_in,
                              void* d_out, int out_size, void* d_ws, size_t ws_size,
                              hipStream_t stream) {
  const float* hs = (const float*)d_in[0];
  const float* nw = (const float*)d_in[1];
  const float* w = (const float*)d_in[2];
  const float* ag = (const float*)d_in[3];
  const float* wg = (const float*)d_in[4];
  float* out = (float*)d_out;  // fp32 resid scratch; final y overwrites in place

  const size_t need_big = ((size_t)3 * HD * HD + (size_t)TD * HD) * sizeof(u16);
  if (ws_size >= need_big) {
    u16* wq3 = (u16*)d_ws;                        // 3*HD*HD bf16 bits (96 MiB)
    u16* yq = wq3 + (size_t)3 * HD * HD;          // TD*HD bf16 bits (64 MiB)
    k_quant_w_all<<<3 * HD, 256, 0, stream>>>(w, wg, wq3);
    k_relu_norm_quant<<<TD / 4, 256, 0, stream>>>(hs, nw, ag, out, yq);
    for (int l = 0; l < 3; ++l) {
      k_gemm<<<dim3((TD / 256) * (HD / 256)), 512, 0, stream>>>(
          yq, wq3 + (size_t)l * HD * HD, out, ag, wg, l);
      if (l < 2) k_norm_quant<<<TD / 4, 256, 0, stream>>>(out, nw, ag, l + 1, yq);
    }
  } else {
    u16* wq = (u16*)d_ws;                    // HD*HD bf16 bits, reused per layer
    u16* yq = (u16*)d_ws + (size_t)HD * HD;  // TD*HD bf16 bits
    k_relu_norm_quant<<<TD / 4, 256, 0, stream>>>(hs, nw, ag, out, yq);
    for (int l = 0; l < 3; ++l) {
      k_quant_w<<<HD, 256, 0, stream>>>(w, wg, l, wq);
      k_gemm<<<dim3((TD / 256) * (HD / 256)), 512, 0, stream>>>(yq, wq, out, ag, wg, l);
      if (l < 2) k_norm_quant<<<TD / 4, 256, 0, stream>>>(out, nw, ag, l + 1, yq);
    }
  }
  k_final_norm<<<TD / 4, 256, 0, stream>>>(out, nw);
}

// Round 4
// 1349.773 us; speedup vs baseline: 1.0336x; 1.0046x over previous
//
#include <hip/hip_runtime.h>
#include <stdint.h>

#define HD 4096
#define TD 8192

typedef unsigned short u16;
typedef unsigned int u32;
typedef __bf16 bf16x8 __attribute__((ext_vector_type(8)));
typedef float f32x4 __attribute__((ext_vector_type(4)));

// async global->LDS, 16B per lane; LDS dest is wave-uniform base + lane*16,
// so lane l's global chunk must map to ldsbase + l*16 (layouts below do).
#define GL16(gp, lp) __builtin_amdgcn_global_load_lds( \
    (__attribute__((address_space(1))) void*)(void*)(uintptr_t)(gp), \
    (__attribute__((address_space(3))) void*)(lp), 16, 0, 0)

// ---------- NVFP4 quantization helpers ----------

// Round f (>=0) to nearest e4m3fn value (RTNE), returned as the decoded float.
__device__ __forceinline__ float e4m3_rtne(float f) {
  if (f <= 0.0f) return 0.0f;
  unsigned u = __float_as_uint(f);
  int e = (int)((u >> 23) & 0xff) - 127;
  if (e < -6) e = -6;
  float C = __uint_as_float((unsigned)(e + 147) << 23);  // 2^(e+20)
  float r = (f + C) - C;
  return fminf(r, 448.0f);
}

// Quantize 16 fp32 values (one NVFP4 block) with global scale g; write 16
// dequantized (q*s8 = dequant*g) values as bf16 bits (exact: <=6 sig bits).
__device__ __forceinline__ void quant_store16(const float v[16], float g, u16* dst) {
  float amax = 0.0f;
#pragma unroll
  for (int j = 0; j < 16; ++j) amax = fmaxf(amax, fabsf(v[j]));
  float s = e4m3_rtne(amax * g / 6.0f);
  u32 out[8];
  if (s > 0.0f) {
    const float m1 = 0.25f * s, m2 = 0.75f * s, m3 = 1.25f * s, m4 = 1.75f * s;
    const float m5 = 2.5f * s, m6 = 3.5f * s, m7 = 5.0f * s;
#pragma unroll
    for (int p = 0; p < 8; ++p) {
      u16 b[2];
#pragma unroll
      for (int h = 0; h < 2; ++h) {
        float t = v[2 * p + h] * g;
        float u = fabsf(t);
        float q = (u < m4) ? ((u < m2) ? ((u < m1) ? 0.0f : 0.5f)
                                       : ((u < m3) ? 1.0f : 1.5f))
                           : ((u < m6) ? ((u < m5) ? 2.0f : 3.0f)
                                       : ((u < m7) ? 4.0f : 6.0f));
        float val = copysignf(q * s, t);
        b[h] = (u16)(__float_as_uint(val) >> 16);  // exact bf16 truncation
      }
      out[p] = (u32)b[0] | ((u32)b[1] << 16);
    }
  } else {
#pragma unroll
    for (int p = 0; p < 8; ++p) out[p] = 0u;
  }
  uint4* d4 = (uint4*)dst;
  d4[0] = make_uint4(out[0], out[1], out[2], out[3]);
  d4[1] = make_uint4(out[4], out[5], out[6], out[7]);
}

// ---------- elementwise / norm kernels (wave-per-row, 4 rows per block) ----------
// Lane owns 4 NVFP4 blocks: cols c*1024 + lane*16 .. +15 (c = 0..3).
// Row reduction is a pure 6-step shfl_xor across the wave: no LDS, no
// __syncthreads -> stores are not serialized behind block-wide barriers.

__global__ __launch_bounds__(256) void k_relu_norm_quant(
    const float* __restrict__ hs, const float* __restrict__ nw,
    const float* __restrict__ agp, float* __restrict__ resid,
    u16* __restrict__ yq) {
  const int lane = threadIdx.x & 63;
  const int row = blockIdx.x * 4 + (threadIdx.x >> 6);
  const size_t base = (size_t)row * HD;
  float v[64];
#pragma unroll
  for (int c = 0; c < 4; ++c)
#pragma unroll
    for (int j = 0; j < 4; ++j)
      ((float4*)v)[c * 4 + j] =
          ((const float4*)(hs + base + c * 1024 + lane * 16))[j];
  float ss = 0.0f;
#pragma unroll
  for (int j = 0; j < 64; ++j) {
    v[j] = fmaxf(v[j], 0.0f);
    ss += v[j] * v[j];
  }
#pragma unroll
  for (int c = 0; c < 4; ++c)
#pragma unroll
    for (int j = 0; j < 4; ++j)
      ((float4*)(resid + base + c * 1024 + lane * 16))[j] = ((float4*)v)[c * 4 + j];
#pragma unroll
  for (int off = 32; off > 0; off >>= 1) ss += __shfl_xor(ss, off, 64);
  const float rs = 1.0f / sqrtf(ss * (1.0f / HD) + 1e-6f);
  const float g = agp[0];
  const float* nwp = nw;  // norm_w[0]
#pragma unroll
  for (int c = 0; c < 4; ++c) {
    float y[16];
#pragma unroll
    for (int j = 0; j < 16; ++j)
      y[j] = v[c * 16 + j] * rs * nwp[c * 1024 + lane * 16 + j];
    quant_store16(y, g, yq + base + c * 1024 + lane * 16);
  }
}

__global__ __launch_bounds__(256) void k_norm_quant(
    const float* __restrict__ resid, const float* __restrict__ nw,
    const float* __restrict__ agp, int li, u16* __restrict__ yq) {
  const int lane = threadIdx.x & 63;
  const int row = blockIdx.x * 4 + (threadIdx.x >> 6);
  const size_t base = (size_t)row * HD;
  float v[64];
#pragma unroll
  for (int c = 0; c < 4; ++c)
#pragma unroll
    for (int j = 0; j < 4; ++j)
      ((float4*)v)[c * 4 + j] =
          ((const float4*)(resid + base + c * 1024 + lane * 16))[j];
  float ss = 0.0f;
#pragma unroll
  for (int j = 0; j < 64; ++j) ss += v[j] * v[j];
#pragma unroll
  for (int off = 32; off > 0; off >>= 1) ss += __shfl_xor(ss, off, 64);
  const float rs = 1.0f / sqrtf(ss * (1.0f / HD) + 1e-6f);
  const float g = agp[li];
  const float* nwp = nw + (size_t)li * HD;
#pragma unroll
  for (int c = 0; c < 4; ++c) {
    float y[16];
#pragma unroll
    for (int j = 0; j < 16; ++j)
      y[j] = v[c * 16 + j] * rs * nwp[c * 1024 + lane * 16 + j];
    quant_store16(y, g, yq + base + c * 1024 + lane * 16);
  }
}

__global__ __launch_bounds__(256) void k_final_norm(
    float* __restrict__ io, const float* __restrict__ nw) {
  const int lane = threadIdx.x & 63;
  const int row = blockIdx.x * 4 + (threadIdx.x >> 6);
  const size_t base = (size_t)row * HD;
  float v[64];
#pragma unroll
  for (int c = 0; c < 4; ++c)
#pragma unroll
    for (int j = 0; j < 4; ++j)
      ((float4*)v)[c * 4 + j] =
          ((const float4*)(io + base + c * 1024 + lane * 16))[j];
  float ss = 0.0f;
#pragma unroll
  for (int j = 0; j < 64; ++j) ss += v[j] * v[j];
#pragma unroll
  for (int off = 32; off > 0; off >>= 1) ss += __shfl_xor(ss, off, 64);
  const float rs = 1.0f / sqrtf(ss * (1.0f / HD) + 1e-6f);
  const float* nwp = nw + (size_t)3 * HD;
#pragma unroll
  for (int c = 0; c < 4; ++c) {
#pragma unroll
    for (int j = 0; j < 16; ++j)
      v[c * 16 + j] = v[c * 16 + j] * rs * nwp[c * 1024 + lane * 16 + j];
#pragma unroll
    for (int j = 0; j < 4; ++j)
      ((float4*)(io + base + c * 1024 + lane * 16))[j] = ((float4*)v)[c * 4 + j];
  }
}

__global__ __launch_bounds__(256) void k_quant_w(
    const float* __restrict__ w, const float* __restrict__ wgp, int li,
    u16* __restrict__ wq) {
  const int row = blockIdx.x, tid = threadIdx.x;
  const size_t base = (size_t)li * HD * HD + (size_t)row * HD + tid * 16;
  float v[16];
#pragma unroll
  for (int j = 0; j < 4; ++j) ((float4*)v)[j] = ((const float4*)(w + base))[j];
  quant_store16(v, wgp[li], wq + (size_t)row * HD + tid * 16);
}

// all 3 layers in one dispatch (rows 0..3*HD); wq3 laid out [l][HD][HD]
__global__ __launch_bounds__(256) void k_quant_w_all(
    const float* __restrict__ w, const float* __restrict__ wgp,
    u16* __restrict__ wq3) {
  const int row = blockIdx.x, tid = threadIdx.x;
  const size_t base = (size_t)row * HD + tid * 16;
  float v[16];
#pragma unroll
  for (int j = 0; j < 4; ++j) ((float4*)v)[j] = ((const float4*)(w + base))[j];
  quant_store16(v, wgp[row >> 12], wq3 + base);
}

// ---------- bf16 GEMM, 256x256, 4-phase schedule: z = A @ B^T, resid += z*alpha ----------
// A [TD, HD] bf16 bits, B [HD, HD] bf16 bits (B row = output col).
// BM=BN=256, BK=64. 8 waves = 2(M) x 4(N); per-wave output 128x64 = 8x4
// mfma_f32_16x16x32_bf16 frags. LDS: 2 buffers x [256 rows][64] bf16 per
// operand = 128 KiB. buf0 holds even K-tiles, buf1 odd (fixed roles).
//
// Swizzle (both-sides, rule #21): 16B chunk kc of row m lives at LDS chunk
// kc ^ (m&7); staging keeps LDS linear and pre-swizzles the GLOBAL source
// column; ds_read_b128 applies the same XOR. (Zero conflicts measured.)
//
// 4 phases per iteration (2 K-tiles: 2i in buf0, 2i+1 in buf1), 32 MFMA and
// 2 barriers per phase (was 16 MFMA / 2 barriers -> barrier count halved):
//   P1 (buf0,mh0): LD a-mh0(8)+b(8); stage buf1.A0,A1[2i+1]; bar; 32 MFMA;
//                  WLG; bar.
//   P2 (buf0,mh1): LD a-mh1(8); stage buf0.B0,B1[2i+2]; vmcnt(4); bar;
//                  32 MFMA; WLG; bar.
//   P3 (buf1,mh0): LD; stage buf0.A0,A1[2i+2]; bar; 32 MFMA; WLG; bar.
//   P4 (buf1,mh1): LD; stage buf1.B0,B1[2i+3]; vmcnt(4); bar; 32 MFMA;
//                  WLG; bar.
// Overwrite safety: every staged region's last reader retired at the
// preceding phase's WLG+barrier (P1 stages buf1.A, last read prev-P4; P2
// stages buf0.B, last read P1; P3 stages buf0.A, last read P2; P4 stages
// buf1.B, last read P3). Same-phase read/stage regions are disjoint.
// vmcnt(4) at P2 retires {prev-P4 buf1.B, P1 buf1.A} -> buf1[2i+1] landed
// before P3 reads it; vmcnt(4) at P4 retires {P2 buf0.B, P3 buf0.A} ->
// buf0[2i+2] landed before next-P1. Per-acc-element MFMA K-order identical
// to the 8-phase version (bit-exact results).

#define BARF() do { asm volatile("" ::: "memory"); \
    __builtin_amdgcn_s_barrier(); \
    asm volatile("" ::: "memory"); } while (0)
#define WLG() asm volatile("s_waitcnt lgkmcnt(0)" ::: "memory")
#define WVM4() asm volatile("s_waitcnt vmcnt(4)" ::: "memory")

__global__ __launch_bounds__(512, 2) void k_gemm(
    const u16* __restrict__ A, const u16* __restrict__ B,
    float* __restrict__ resid, const float* __restrict__ agp,
    const float* __restrict__ wgp, int layer) {
  __shared__ __align__(16) u16 ldsA[2 * 256 * 64];  // [buf][row][64]
  __shared__ __align__(16) u16 ldsB[2 * 256 * 64];
  const int tid = threadIdx.x;
  const int lane = tid & 63, wave = tid >> 6;
  const int wr = wave >> 2, wc = wave & 3;     // 2 x 4 wave grid
  const int r = lane & 15, q = lane >> 4;

  int bid = blockIdx.x;
  bid = (bid & 7) * 64 + (bid >> 3);  // XCD-contiguous chunks (512 % 8 == 0)
  const int m0 = (bid >> 4) * 256;
  const int n0 = (bid & 15) * 256;

  // ---- staging constants: chunk c=tid (+512) -> lds half-tile byte c*16;
  // global row = half*128 + (c>>3), colchunk = (c&7) ^ ((c>>3)&7).
  const int rs = tid >> 3;
  const int cs = ((tid & 7) ^ (rs & 7)) * 8;
  const u16* gA = A + (size_t)(m0 + rs) * HD + cs;
  const u16* gB = B + (size_t)(n0 + rs) * HD + cs;
  u16* lA = ldsA + tid * 8;
  u16* lB = ldsB + tid * 8;

#define STG_A(bb, h, koff) do { \
    GL16(gA + (size_t)(h) * (128 * HD) + (koff), lA + (bb) + (h) * 8192); \
    GL16(gA + (size_t)(h) * (128 * HD) + 64 * HD + (koff), lA + (bb) + (h) * 8192 + 4096); \
  } while (0)
#define STG_B(bb, h, koff) do { \
    GL16(gB + (size_t)(h) * (128 * HD) + (koff), lB + (bb) + (h) * 8192); \
    GL16(gB + (size_t)(h) * (128 * HD) + 64 * HD + (koff), lB + (bb) + (h) * 8192 + 4096); \
  } while (0)

  // ---- fragment-read constants (element offsets into a 256x64 buffer)
  const int sa = (q ^ (r & 7)) * 8;        // kk=0 swizzled chunk
  const int sb = ((q + 4) ^ (r & 7)) * 8;  // kk=1
  const int arow = (wr * 128 + r) * 64;
  const int brow = (wc * 64 + r) * 64;

  f32x4 acc[8][4];
#pragma unroll
  for (int i = 0; i < 8; ++i)
#pragma unroll
    for (int j = 0; j < 4; ++j) acc[i][j] = (f32x4){0.f, 0.f, 0.f, 0.f};

  bf16x8 a[4][2], b[4][2];

  // a-fragment rows for half mh: wr*128 + mh*64 + mi*16 + r  (mh*64 rows = 4096 elems)
#define LD_AH(base, mh) do { \
    _Pragma("unroll") \
    for (int mi = 0; mi < 4; ++mi) { \
      a[mi][0] = *(const bf16x8*)((base) + arow + (mh) * 4096 + mi * 1024 + sa); \
      a[mi][1] = *(const bf16x8*)((base) + arow + (mh) * 4096 + mi * 1024 + sb); \
    } } while (0)
#define LD_B(base) do { \
    _Pragma("unroll") \
    for (int nj = 0; nj < 4; ++nj) { \
      b[nj][0] = *(const bf16x8*)((base) + brow + nj * 1024 + sa); \
      b[nj][1] = *(const bf16x8*)((base) + brow + nj * 1024 + sb); \
    } } while (0)
#define MMQ(mh, nh) do { \
    _Pragma("unroll") \
    for (int mi = 0; mi < 4; ++mi) \
    _Pragma("unroll") \
    for (int nj = 0; nj < 2; ++nj) { \
      acc[(mh) * 4 + mi][(nh) * 2 + nj] = __builtin_amdgcn_mfma_f32_16x16x32_bf16( \
          a[mi][0], b[(nh) * 2 + nj][0], acc[(mh) * 4 + mi][(nh) * 2 + nj], 0, 0, 0); \
      acc[(mh) * 4 + mi][(nh) * 2 + nj] = __builtin_amdgcn_mfma_f32_16x16x32_bf16( \
          a[mi][1], b[(nh) * 2 + nj][1], acc[(mh) * 4 + mi][(nh) * 2 + nj], 0, 0, 0); \
    } } while (0)

  // ---- prologue: tile0 -> buf0 (B+A), tile1 -> buf1 (B only; A staged in P1).
  // vmcnt(4) retires buf0's 8 loads; buf1.B's 4 stay in flight (= steady state).
  STG_B(0, 0, 0); STG_B(0, 1, 0);
  STG_A(0, 0, 0); STG_A(0, 1, 0);
  STG_B(16384, 0, 64); STG_B(16384, 1, 64);
  WVM4();
  BARF();

  for (int i = 0; i < 32; ++i) {
    const int kb = i * 128;
    const int k1 = kb + 64;                       // tile 2i+1 (never wraps)
    int k2 = kb + 128; if (k2 >= HD) k2 -= HD;    // tile 2i+2 (wrap last iter)
    int k3 = kb + 192; if (k3 >= HD) k3 -= HD;    // tile 2i+3
    // P1: buf0 mh0; stage buf1.A[2i+1]
    LD_AH(ldsA, 0); LD_B(ldsB);
    STG_A(16384, 0, k1); STG_A(16384, 1, k1);
    BARF();
    __builtin_amdgcn_s_setprio(1); MMQ(0, 0); MMQ(0, 1); __builtin_amdgcn_s_setprio(0);
    WLG();
    BARF();
    // P2: buf0 mh1; stage buf0.B[2i+2]; vmcnt(4) -> buf1[2i+1] fully landed
    LD_AH(ldsA, 1);
    STG_B(0, 0, k2); STG_B(0, 1, k2);
    WVM4();
    BARF();
    __builtin_amdgcn_s_setprio(1); MMQ(1, 0); MMQ(1, 1); __builtin_amdgcn_s_setprio(0);
    WLG();
    BARF();
    // P3: buf1 mh0; stage buf0.A[2i+2]
    LD_AH(ldsA + 16384, 0); LD_B(ldsB + 16384);
    STG_A(0, 0, k2); STG_A(0, 1, k2);
    BARF();
    __builtin_amdgcn_s_setprio(1); MMQ(0, 0); MMQ(0, 1); __builtin_amdgcn_s_setprio(0);
    WLG();
    BARF();
    // P4: buf1 mh1; stage buf1.B[2i+3]; vmcnt(4) -> buf0[2i+2] fully landed
    LD_AH(ldsA + 16384, 1);
    STG_B(16384, 0, k3); STG_B(16384, 1, k3);
    WVM4();
    BARF();
    __builtin_amdgcn_s_setprio(1); MMQ(1, 0); MMQ(1, 1); __builtin_amdgcn_s_setprio(0);
    WLG();
    BARF();
  }

  const float alpha = 1.0f / (agp[layer] * wgp[layer]);
  // C/D layout: col = lane&15 (n), row = (lane>>4)*4 + reg (m)
#pragma unroll
  for (int mi = 0; mi < 8; ++mi) {
    const int gm0 = m0 + wr * 128 + mi * 16 + q * 4;
#pragma unroll
    for (int nj = 0; nj < 4; ++nj) {
      const int gn = n0 + wc * 64 + nj * 16 + r;
#pragma unroll
      for (int t = 0; t < 4; ++t) {
        float* p = resid + (size_t)(gm0 + t) * HD + gn;
        *p = fmaf(acc[mi][nj][t], alpha, *p);
      }
    }
  }
}

// ---------- host ----------

extern "C" void kernel_launch(void* const* d_in, const int* in_sizes, int n_in,
                              void* d_out, int out_size, void* d_ws, size_t ws_size,
                              hipStream_t stream) {
  const float* hs = (const float*)d_in[0];
  const float* nw = (const float*)d_in[1];
  const float* w = (const float*)d_in[2];
  const float* ag = (const float*)d_in[3];
  const float* wg = (const float*)d_in[4];
  float* out = (float*)d_out;  // fp32 resid scratch; final y overwrites in place

  const size_t need_big = ((size_t)3 * HD * HD + (size_t)TD * HD) * sizeof(u16);
  if (ws_size >= need_big) {
    u16* wq3 = (u16*)d_ws;                        // 3*HD*HD bf16 bits (96 MiB)
    u16* yq = wq3 + (size_t)3 * HD * HD;          // TD*HD bf16 bits (64 MiB)
    k_quant_w_all<<<3 * HD, 256, 0, stream>>>(w, wg, wq3);
    k_relu_norm_quant<<<TD / 4, 256, 0, stream>>>(hs, nw, ag, out, yq);
    for (int l = 0; l < 3; ++l) {
      k_gemm<<<dim3((TD / 256) * (HD / 256)), 512, 0, stream>>>(
          yq, wq3 + (size_t)l * HD * HD, out, ag, wg, l);
      if (l < 2) k_norm_quant<<<TD / 4, 256, 0, stream>>>(out, nw, ag, l + 1, yq);
    }
  } else {
    u16* wq = (u16*)d_ws;                    // HD*HD bf16 bits, reused per layer
    u16* yq = (u16*)d_ws + (size_t)HD * HD;  // TD*HD bf16 bits
    k_relu_norm_quant<<<TD / 4, 256, 0, stream>>>(hs, nw, ag, out, yq);
    for (int l = 0; l < 3; ++l) {
      k_quant_w<<<HD, 256, 0, stream>>>(w, wg, l, wq);
      k_gemm<<<dim3((TD / 256) * (HD / 256)), 512, 0, stream>>>(yq, wq, out, ag, wg, l);
      if (l < 2) k_norm_quant<<<TD / 4, 256, 0, stream>>>(out, nw, ag, l + 1, yq);
    }
  }
  k_final_norm<<<TD / 4, 256, 0, stream>>>(out, nw);
}